// Round 8
// baseline (168.252 us; speedup 1.0000x reference)
//
#include <hip/hip_runtime.h>
#include <hip/hip_bf16.h>
#include <math.h>

#define NPTS 524288
#define HDIM 256
#define NBLK1 (NPTS / 256)        // 2048 blocks, 1 point per thread
#define STEPS 100

constexpr float DXF        = (float)(20.0 / (NPTS - 1));
constexpr float DTF        = 0.01f;
constexpr float SQRT2DT    = 0.14142135623730951f;       // np.float32(sqrt(2*DT))
constexpr float TWO_LOG2E  = 2.8853900817779268f;        // 2*log2(e)
constexpr float LN2_O_2DX  = (float)(0.6931471805599453 / (2.0 * (20.0 / (NPTS - 1))));

typedef float v2f __attribute__((ext_vector_type(2)));

static __device__ __forceinline__ v2f vfma(v2f a, v2f b, v2f c) {
#if __has_builtin(__builtin_elementwise_fma)
    return __builtin_elementwise_fma(a, b, c);
#else
    v2f r; r.x = fmaf(a.x, b.x, c.x); r.y = fmaf(a.y, b.y, c.y); return r;
#endif
}

// ---------------------------------------------------------------------------
// Kernel 0: fold constants + zero the last-block counter.
// wk (256 floats each): w1k|b1k|w20|w21|wg0|wg1
// ---------------------------------------------------------------------------
__global__ void qpe_prep(const float* __restrict__ W1, const float* __restrict__ b1,
                         const float* __restrict__ W2, float* __restrict__ wk,
                         int* __restrict__ cnt)
{
    const int h = threadIdx.x;
    const float w1  = W1[h];
    const float w20 = W2[2*h];
    const float w21 = W2[2*h + 1];
    const float w1s = w1 * w1;
    wk[h]        = w1 * TWO_LOG2E;
    wk[256 + h]  = b1[h] * TWO_LOG2E;
    wk[512 + h]  = w20;
    wk[768 + h]  = w21;
    wk[1024 + h] = w20 * w1s;
    wk[1280 + h] = w21 * w1s;
    if (h == 0) *cnt = 0;
}

// ---------------------------------------------------------------------------
// Kernel 1: 1 grid point per thread (2048 blocks -> 8 blocks/CU), packed
// fp32 over h-pairs. Writes h_psi, lp2 = log2(nd), block partials. The
// LAST block to finish (threadfence+atomicAdd) becomes the finisher:
//   wave0.lane0: 100-step lookup walk   wave1: energy reduce
//   waves2-3   : warm 1 MB lp2 window into this CU's L1/L2
// ---------------------------------------------------------------------------
__global__ __launch_bounds__(256, 8) void qpe_main(
    const float* __restrict__ x,     const float* __restrict__ V,
    const float* __restrict__ wk,    const float* __restrict__ b2,
    float* __restrict__ out,         float* __restrict__ lp2,
    float* __restrict__ pdens,       float* __restrict__ pnd,
    const float* __restrict__ noise, const int* __restrict__ init_idx,
    int* __restrict__ cnt,           float* __restrict__ dummy)
{
    const int i = blockIdx.x * 256 + threadIdx.x;
    const float xi = x[i];
    const float Vi = V[i];

    const v2f* __restrict__ w1k2 = (const v2f*)(wk);
    const v2f* __restrict__ b1k2 = (const v2f*)(wk + 256);
    const v2f* __restrict__ w202 = (const v2f*)(wk + 512);
    const v2f* __restrict__ w212 = (const v2f*)(wk + 768);
    const v2f* __restrict__ wg02 = (const v2f*)(wk + 1024);
    const v2f* __restrict__ wg12 = (const v2f*)(wk + 1280);

    const v2f x2   = {xi, xi};
    const v2f one2 = {1.0f, 1.0f};
    const v2f m2   = {-2.0f, -2.0f};
    v2f p0 = {0.f,0.f}, p1 = {0.f,0.f}, a0 = {0.f,0.f}, a1 = {0.f,0.f};

    #pragma unroll 4
    for (int j = 0; j < HDIM / 2; ++j) {
        const v2f u = vfma(x2, w1k2[j], b1k2[j]);
        v2f e; e.x = __builtin_amdgcn_exp2f(u.x); e.y = __builtin_amdgcn_exp2f(u.y);
        const v2f dd = e + one2;
        v2f r; r.x = __builtin_amdgcn_rcpf(dd.x); r.y = __builtin_amdgcn_rcpf(dd.y);
        const v2f t = vfma(m2, r, one2);            // tanh
        const v2f o = vfma(-t, t, one2);            // 1 - t^2
        const v2f g = t * o;                        // t(1-t^2)
        p0 = vfma(w202[j], t, p0);
        p1 = vfma(w212[j], t, p1);
        a0 = vfma(wg02[j], g, a0);
        a1 = vfma(wg12[j], g, a1);
    }

    const float psi0 = p0.x + p0.y + b2[0];
    const float psi1 = p1.x + p1.y + b2[1];
    const float ta0  = a0.x + a0.y;
    const float ta1  = a1.x + a1.y;

    const float hp0 = fmaf(Vi, psi0, ta0);          // h_psi = K*lap + V*psi
    const float hp1 = fmaf(Vi, psi1, ta1);
    reinterpret_cast<float2*>(out)[i] = make_float2(hp0, hp1);

    const float nd = fmaf(psi0, psi0, psi1 * psi1);
    lp2[i] = __builtin_amdgcn_logf(nd);             // log2(nd)

    float dens = fmaf(psi0, hp0, psi1 * hp1);
    float ndr  = nd;
    #pragma unroll
    for (int off = 32; off; off >>= 1) {
        dens += __shfl_down(dens, off);
        ndr  += __shfl_down(ndr, off);
    }
    __shared__ float sd[4], sn[4];
    const int tid  = threadIdx.x;
    const int lane = tid & 63;
    const int wid  = tid >> 6;
    if (lane == 0) { sd[wid] = dens; sn[wid] = ndr; }
    __syncthreads();
    if (tid == 0) {
        pdens[blockIdx.x] = sd[0] + sd[1] + sd[2] + sd[3];
        pnd[blockIdx.x]   = sn[0] + sn[1] + sn[2] + sn[3];
    }

    // ---- last-block election (standard threadfence + atomicAdd idiom) ----
    __shared__ int lastflag;
    if (tid == 0) {
        __threadfence();                            // release our writes
        lastflag = (atomicAdd(cnt, 1) == NBLK1 - 1);
    }
    __syncthreads();
    if (!lastflag) return;
    __threadfence();                                // acquire others' writes

    if (tid == 0) {
        // 100-step lookup walk (bit-identical math to the passing R5/R6)
        int c = init_idx[0];
        float zn = noise[0];
        for (int t = 0; t < STEPS; ++t) {
            const float zs = __fmul_rn(zn, SQRT2DT);
            const int tn = (t + 1 < STEPS) ? t + 1 : t;
            zn = noise[tn];                         // prefetch next noise
            float s = 0.0f;
            if (c > 0 && c < NPTS - 1) {
                const float l2m = lp2[c - 1];
                const float l2p = lp2[c + 1];
                s = __fmul_rn(__fsub_rn(l2p, l2m), LN2_O_2DX);
            }
            const float a = __fadd_rn(__fmul_rn(s, DTF), zs);
            const int shift = (int)__fdiv_rn(a, DXF);
            c += shift;
            c = c < 0 ? 0 : (c > NPTS - 1 ? NPTS - 1 : c);
        }
        out[2 * NPTS + 1] = x[c];
    } else if (tid >= 64 && tid < 128) {
        // energy reduce over 2048 block partials
        const int l = tid - 64;
        float d = 0.f, n = 0.f;
        #pragma unroll 8
        for (int k = 0; k < 32; ++k) {
            d += pdens[l + 64 * k];
            n += pnd[l + 64 * k];
        }
        #pragma unroll
        for (int off = 32; off; off >>= 1) {
            d += __shfl_down(d, off);
            n += __shfl_down(n, off);
        }
        if (l == 0)
            out[2 * NPTS] = __fdiv_rn(d * DXF, fmaf(n, DXF, 1e-8f));
    } else if (tid >= 128) {
        // warm 1 MB (64K float4) of lp2 around init_idx into local L1/L2
        int c0 = init_idx[0];
        int s4 = c0 / 4 - 32768;
        if (s4 < 0) s4 = 0;
        if (s4 > NPTS / 4 - 65536) s4 = NPTS / 4 - 65536;
        const float4* __restrict__ src = (const float4*)lp2 + s4;
        const int l = tid - 128;                    // 0..127
        float acc = 0.f;
        #pragma unroll 8
        for (int k = l; k < 65536; k += 128) {
            const float4 v = src[k];
            acc += v.x + v.y + v.z + v.w;
        }
        if (acc == 123456.789f) dummy[0] = acc;     // keep loads alive
    }
}

// ---------------------------------------------------------------------------
extern "C" void kernel_launch(void* const* d_in, const int* in_sizes, int n_in,
                              void* d_out, int out_size, void* d_ws, size_t ws_size,
                              hipStream_t stream) {
    const float* x        = (const float*)d_in[0];
    const float* V        = (const float*)d_in[1];
    const float* W1       = (const float*)d_in[2];
    const float* b1       = (const float*)d_in[3];
    const float* W2       = (const float*)d_in[4];
    const float* b2       = (const float*)d_in[5];
    const float* noise    = (const float*)d_in[6];
    const int*   init_idx = (const int*)d_in[7];

    float* out = (float*)d_out;
    float* ws  = (float*)d_ws;

    float* lp2   = ws;                      // N floats (2 MB)
    float* wk    = ws + NPTS;               // 1536 (pad to 2048)
    float* pdens = ws + NPTS + 2048;        // 2048
    float* pnd   = ws + NPTS + 4096;        // 2048
    int*   cnt   = (int*)(ws + NPTS + 6144);
    float* dummy = ws + NPTS + 6145;

    qpe_prep<<<1, 256, 0, stream>>>(W1, b1, W2, wk, cnt);
    qpe_main<<<NBLK1, 256, 0, stream>>>(x, V, wk, b2, out, lp2, pdens, pnd,
                                        noise, init_idx, cnt, dummy);
}

// Round 13
// 132.938 us; speedup vs baseline: 1.2656x; 1.2656x over previous
//
#include <hip/hip_runtime.h>
#include <hip/hip_bf16.h>
#include <math.h>

#define NPTS 524288
#define HDIM 256
#define NBLK1 (NPTS / 256)        // 2048 blocks, 1 point per thread
#define STEPS 100

constexpr float DXF        = (float)(20.0 / (NPTS - 1));
constexpr float DTF        = 0.01f;
constexpr float SQRT2DT    = 0.14142135623730951f;       // np.float32(sqrt(2*DT))
constexpr float TWO_LOG2E  = 2.8853900817779268f;        // 2*log2(e)
constexpr float LN2_O_2DX  = (float)(0.6931471805599453 / (2.0 * (20.0 / (NPTS - 1))));

typedef float v2f __attribute__((ext_vector_type(2)));

static __device__ __forceinline__ v2f vfma(v2f a, v2f b, v2f c) {
#if __has_builtin(__builtin_elementwise_fma)
    return __builtin_elementwise_fma(a, b, c);
#else
    v2f r; r.x = fmaf(a.x, b.x, c.x); r.y = fmaf(a.y, b.y, c.y); return r;
#endif
}

// ---------------------------------------------------------------------------
// Kernel 0: fold constants. wk (256 floats each): w1k|b1k|w20|w21|wg0|wg1
// ---------------------------------------------------------------------------
__global__ void qpe_prep(const float* __restrict__ W1, const float* __restrict__ b1,
                         const float* __restrict__ W2, float* __restrict__ wk)
{
    const int h = threadIdx.x;
    const float w1  = W1[h];
    const float w20 = W2[2*h];
    const float w21 = W2[2*h + 1];
    const float w1s = w1 * w1;
    wk[h]        = w1 * TWO_LOG2E;
    wk[256 + h]  = b1[h] * TWO_LOG2E;
    wk[512 + h]  = w20;
    wk[768 + h]  = w21;
    wk[1024 + h] = w20 * w1s;
    wk[1280 + h] = w21 * w1s;
}

// ---------------------------------------------------------------------------
// Kernel 1: 1 grid point per thread (2048 blocks -> max TLP, the measured
// occupancy sweet spot from R1) x packed h-pair math (the issue-count win
// from R2). No register-capping launch bounds. Writes h_psi, lp2 = log2(nd),
// and per-block partials.
// ---------------------------------------------------------------------------
__global__ __launch_bounds__(256) void qpe_main(
    const float* __restrict__ x,  const float* __restrict__ V,
    const float* __restrict__ wk, const float* __restrict__ b2,
    float* __restrict__ out,      float* __restrict__ lp2,
    float* __restrict__ pdens,    float* __restrict__ pnd)
{
    const int i = blockIdx.x * 256 + threadIdx.x;
    const float xi = x[i];
    const float Vi = V[i];

    const v2f* __restrict__ w1k2 = (const v2f*)(wk);
    const v2f* __restrict__ b1k2 = (const v2f*)(wk + 256);
    const v2f* __restrict__ w202 = (const v2f*)(wk + 512);
    const v2f* __restrict__ w212 = (const v2f*)(wk + 768);
    const v2f* __restrict__ wg02 = (const v2f*)(wk + 1024);
    const v2f* __restrict__ wg12 = (const v2f*)(wk + 1280);

    const v2f x2   = {xi, xi};
    const v2f one2 = {1.0f, 1.0f};
    const v2f m2   = {-2.0f, -2.0f};
    v2f p0 = {0.f,0.f}, p1 = {0.f,0.f}, a0 = {0.f,0.f}, a1 = {0.f,0.f};

    #pragma unroll 8
    for (int j = 0; j < HDIM / 2; ++j) {
        const v2f u = vfma(x2, w1k2[j], b1k2[j]);
        v2f e; e.x = __builtin_amdgcn_exp2f(u.x); e.y = __builtin_amdgcn_exp2f(u.y);
        const v2f dd = e + one2;
        v2f r; r.x = __builtin_amdgcn_rcpf(dd.x); r.y = __builtin_amdgcn_rcpf(dd.y);
        const v2f t = vfma(m2, r, one2);            // tanh
        const v2f o = vfma(-t, t, one2);            // 1 - t^2
        const v2f g = t * o;                        // t(1-t^2)
        p0 = vfma(w202[j], t, p0);
        p1 = vfma(w212[j], t, p1);
        a0 = vfma(wg02[j], g, a0);
        a1 = vfma(wg12[j], g, a1);
    }

    const float psi0 = p0.x + p0.y + b2[0];
    const float psi1 = p1.x + p1.y + b2[1];
    const float ta0  = a0.x + a0.y;
    const float ta1  = a1.x + a1.y;

    const float hp0 = fmaf(Vi, psi0, ta0);          // h_psi = K*lap + V*psi
    const float hp1 = fmaf(Vi, psi1, ta1);
    reinterpret_cast<float2*>(out)[i] = make_float2(hp0, hp1);

    const float nd = fmaf(psi0, psi0, psi1 * psi1);
    lp2[i] = __builtin_amdgcn_logf(nd);             // log2(nd)

    float dens = fmaf(psi0, hp0, psi1 * hp1);
    float ndr  = nd;
    #pragma unroll
    for (int off = 32; off; off >>= 1) {
        dens += __shfl_down(dens, off);
        ndr  += __shfl_down(ndr, off);
    }
    __shared__ float sd[4], sn[4];
    const int lane = threadIdx.x & 63;
    const int wid  = threadIdx.x >> 6;
    if (lane == 0) { sd[wid] = dens; sn[wid] = ndr; }
    __syncthreads();
    if (threadIdx.x == 0) {
        pdens[blockIdx.x] = sd[0] + sd[1] + sd[2] + sd[3];
        pnd[blockIdx.x]   = sn[0] + sn[1] + sn[2] + sn[3];
    }
}

// ---------------------------------------------------------------------------
// Kernel 2, 2 blocks:
//   block0          : reduce 2048 partials -> energy (~3 us, hidden)
//   block1 wave0.l0 : 100-step lookup walk on lp2 (2 adjacent loads + ~10
//                     VALU per step; L2-hit after the warm lands)
//   block1 waves1-3 : warm 512 KB of lp2 around init_idx into this XCD's
//                     L2 (~1.8 sigma of the walk's diffusion; excursions
//                     outside just pay L3 latency, never wrong results)
// ---------------------------------------------------------------------------
__global__ __launch_bounds__(256) void qpe_tail(
    const float* __restrict__ x,     const float* __restrict__ lp2,
    const float* __restrict__ pdens, const float* __restrict__ pnd,
    const float* __restrict__ noise, const int* __restrict__ init_idx,
    float* __restrict__ out,         float* __restrict__ dummy)
{
    const int tid = threadIdx.x;
    if (blockIdx.x == 0) {
        float d = 0.f, n = 0.f;
        #pragma unroll
        for (int k = 0; k < 8; ++k) {
            d += pdens[tid + 256 * k];
            n += pnd[tid + 256 * k];
        }
        #pragma unroll
        for (int off = 32; off; off >>= 1) {
            d += __shfl_down(d, off);
            n += __shfl_down(n, off);
        }
        __shared__ float sd[4], sn[4];
        const int lane = tid & 63;
        const int wid  = tid >> 6;
        if (lane == 0) { sd[wid] = d; sn[wid] = n; }
        __syncthreads();
        if (tid == 0) {
            const float Sd = sd[0] + sd[1] + sd[2] + sd[3];
            const float Sn = sn[0] + sn[1] + sn[2] + sn[3];
            out[2 * NPTS] = __fdiv_rn(Sd * DXF, fmaf(Sn, DXF, 1e-8f));
        }
        return;
    }

    if (tid == 0) {
        int c = init_idx[0];
        float zn = noise[0];
        for (int t = 0; t < STEPS; ++t) {
            const float zs = __fmul_rn(zn, SQRT2DT);
            const int tn = (t + 1 < STEPS) ? t + 1 : t;
            zn = noise[tn];                  // prefetch next step's noise
            float s = 0.0f;
            if (c > 0 && c < NPTS - 1) {
                const float l2m = lp2[c - 1];
                const float l2p = lp2[c + 1];
                s = __fmul_rn(__fsub_rn(l2p, l2m), LN2_O_2DX);
            }
            const float a = __fadd_rn(__fmul_rn(s, DTF), zs);
            const int shift = (int)__fdiv_rn(a, DXF);
            c += shift;
            c = c < 0 ? 0 : (c > NPTS - 1 ? NPTS - 1 : c);
        }
        out[2 * NPTS + 1] = x[c];
    } else if (tid >= 64) {
        // warm 512 KB (32K float4) of lp2 around init_idx, 8-deep pipeline
        int c0 = init_idx[0];
        int s4 = c0 / 4 - 16384;             // window start in float4 units
        if (s4 < 0) s4 = 0;
        if (s4 > NPTS / 4 - 32768) s4 = NPTS / 4 - 32768;
        const float4* __restrict__ src = (const float4*)lp2 + s4;
        const int l = tid - 64;              // 0..191
        float acc = 0.f;
        #pragma unroll 8
        for (int k = l; k < 32768; k += 192) {
            const float4 v = src[k];
            acc += v.x + v.y + v.z + v.w;
        }
        if (acc == 123456.789f) dummy[0] = acc;   // keep loads alive
    }
}

// ---------------------------------------------------------------------------
extern "C" void kernel_launch(void* const* d_in, const int* in_sizes, int n_in,
                              void* d_out, int out_size, void* d_ws, size_t ws_size,
                              hipStream_t stream) {
    const float* x        = (const float*)d_in[0];
    const float* V        = (const float*)d_in[1];
    const float* W1       = (const float*)d_in[2];
    const float* b1       = (const float*)d_in[3];
    const float* W2       = (const float*)d_in[4];
    const float* b2       = (const float*)d_in[5];
    const float* noise    = (const float*)d_in[6];
    const int*   init_idx = (const int*)d_in[7];

    float* out = (float*)d_out;
    float* ws  = (float*)d_ws;

    float* lp2   = ws;                      // N floats (2 MB)
    float* wk    = ws + NPTS;               // 1536 (pad to 2048)
    float* pdens = ws + NPTS + 2048;        // 2048
    float* pnd   = ws + NPTS + 4096;        // 2048
    float* dummy = ws + NPTS + 6144;        // 1

    qpe_prep<<<1, 256, 0, stream>>>(W1, b1, W2, wk);
    qpe_main<<<NBLK1, 256, 0, stream>>>(x, V, wk, b2, out, lp2, pdens, pnd);
    qpe_tail<<<2, 256, 0, stream>>>(x, lp2, pdens, pnd, noise, init_idx,
                                    out, dummy);
}

// Round 14
// 130.091 us; speedup vs baseline: 1.2933x; 1.0219x over previous
//
#include <hip/hip_runtime.h>
#include <hip/hip_bf16.h>
#include <math.h>

#define NPTS 524288
#define HDIM 256
#define NBLK1 (NPTS / 256)        // 2048 blocks, 1 point per thread
#define STEPS 100

constexpr float DXF        = (float)(20.0 / (NPTS - 1));
constexpr float DTF        = 0.01f;
constexpr float SQRT2DT    = 0.14142135623730951f;       // np.float32(sqrt(2*DT))
constexpr float TWO_LOG2E  = 2.8853900817779268f;        // 2*log2(e)
constexpr float LN2_O_2DX  = (float)(0.6931471805599453 / (2.0 * (20.0 / (NPTS - 1))));

typedef float v2f __attribute__((ext_vector_type(2)));

static __device__ __forceinline__ v2f vfma(v2f a, v2f b, v2f c) {
#if __has_builtin(__builtin_elementwise_fma)
    return __builtin_elementwise_fma(a, b, c);
#else
    v2f r; r.x = fmaf(a.x, b.x, c.x); r.y = fmaf(a.y, b.y, c.y); return r;
#endif
}

// ---------------------------------------------------------------------------
// Kernel 0: fold constants. wk (256 floats each): w1k|b1k|w20|w21|wg0|wg1
// ---------------------------------------------------------------------------
__global__ void qpe_prep(const float* __restrict__ W1, const float* __restrict__ b1,
                         const float* __restrict__ W2, float* __restrict__ wk)
{
    const int h = threadIdx.x;
    const float w1  = W1[h];
    const float w20 = W2[2*h];
    const float w21 = W2[2*h + 1];
    const float w1s = w1 * w1;
    wk[h]        = w1 * TWO_LOG2E;
    wk[256 + h]  = b1[h] * TWO_LOG2E;
    wk[512 + h]  = w20;
    wk[768 + h]  = w21;
    wk[1024 + h] = w20 * w1s;
    wk[1280 + h] = w21 * w1s;
}

// ---------------------------------------------------------------------------
// Kernel 1: 1 grid point per thread at 2048 blocks (the measured TLP
// sweet spot) x TWO INDEPENDENT H-STREAMS per thread (h-pairs j and j+64):
// two exp2->rcp dependency chains fill the trans-latency gaps that left
// VALUBusy at 64-66% in every single-chain variant (R5/R8). Grid unchanged,
// ILP doubled -- the untried corner of the measured design space.
// ---------------------------------------------------------------------------
__global__ __launch_bounds__(256) void qpe_main(
    const float* __restrict__ x,  const float* __restrict__ V,
    const float* __restrict__ wk, const float* __restrict__ b2,
    float* __restrict__ out,      float* __restrict__ lp2,
    float* __restrict__ pdens,    float* __restrict__ pnd)
{
    const int i = blockIdx.x * 256 + threadIdx.x;
    const float xi = x[i];
    const float Vi = V[i];

    const v2f* __restrict__ w1k2 = (const v2f*)(wk);
    const v2f* __restrict__ b1k2 = (const v2f*)(wk + 256);
    const v2f* __restrict__ w202 = (const v2f*)(wk + 512);
    const v2f* __restrict__ w212 = (const v2f*)(wk + 768);
    const v2f* __restrict__ wg02 = (const v2f*)(wk + 1024);
    const v2f* __restrict__ wg12 = (const v2f*)(wk + 1280);

    const v2f x2   = {xi, xi};
    const v2f one2 = {1.0f, 1.0f};
    const v2f m2   = {-2.0f, -2.0f};
    v2f p0A = {0.f,0.f}, p1A = {0.f,0.f}, a0A = {0.f,0.f}, a1A = {0.f,0.f};
    v2f p0B = {0.f,0.f}, p1B = {0.f,0.f}, a0B = {0.f,0.f}, a1B = {0.f,0.f};

    #pragma unroll 4
    for (int j = 0; j < HDIM / 4; ++j) {
        const int jb = j + HDIM / 4;                 // second h-stream
        const v2f uA = vfma(x2, w1k2[j],  b1k2[j]);
        const v2f uB = vfma(x2, w1k2[jb], b1k2[jb]);
        v2f eA, eB;
        eA.x = __builtin_amdgcn_exp2f(uA.x); eA.y = __builtin_amdgcn_exp2f(uA.y);
        eB.x = __builtin_amdgcn_exp2f(uB.x); eB.y = __builtin_amdgcn_exp2f(uB.y);
        const v2f dA = eA + one2;
        const v2f dB = eB + one2;
        v2f rA, rB;
        rA.x = __builtin_amdgcn_rcpf(dA.x); rA.y = __builtin_amdgcn_rcpf(dA.y);
        rB.x = __builtin_amdgcn_rcpf(dB.x); rB.y = __builtin_amdgcn_rcpf(dB.y);
        const v2f tA = vfma(m2, rA, one2);           // tanh
        const v2f tB = vfma(m2, rB, one2);
        const v2f oA = vfma(-tA, tA, one2);          // 1 - t^2
        const v2f oB = vfma(-tB, tB, one2);
        const v2f gA = tA * oA;                      // t(1-t^2)
        const v2f gB = tB * oB;
        p0A = vfma(w202[j],  tA, p0A);
        p1A = vfma(w212[j],  tA, p1A);
        a0A = vfma(wg02[j],  gA, a0A);
        a1A = vfma(wg12[j],  gA, a1A);
        p0B = vfma(w202[jb], tB, p0B);
        p1B = vfma(w212[jb], tB, p1B);
        a0B = vfma(wg02[jb], gB, a0B);
        a1B = vfma(wg12[jb], gB, a1B);
    }

    const v2f p0 = p0A + p0B;
    const v2f p1 = p1A + p1B;
    const v2f a0 = a0A + a0B;
    const v2f a1 = a1A + a1B;

    const float psi0 = p0.x + p0.y + b2[0];
    const float psi1 = p1.x + p1.y + b2[1];
    const float ta0  = a0.x + a0.y;
    const float ta1  = a1.x + a1.y;

    const float hp0 = fmaf(Vi, psi0, ta0);          // h_psi = K*lap + V*psi
    const float hp1 = fmaf(Vi, psi1, ta1);
    reinterpret_cast<float2*>(out)[i] = make_float2(hp0, hp1);

    const float nd = fmaf(psi0, psi0, psi1 * psi1);
    lp2[i] = __builtin_amdgcn_logf(nd);             // log2(nd)

    float dens = fmaf(psi0, hp0, psi1 * hp1);
    float ndr  = nd;
    #pragma unroll
    for (int off = 32; off; off >>= 1) {
        dens += __shfl_down(dens, off);
        ndr  += __shfl_down(ndr, off);
    }
    __shared__ float sd[4], sn[4];
    const int lane = threadIdx.x & 63;
    const int wid  = threadIdx.x >> 6;
    if (lane == 0) { sd[wid] = dens; sn[wid] = ndr; }
    __syncthreads();
    if (threadIdx.x == 0) {
        pdens[blockIdx.x] = sd[0] + sd[1] + sd[2] + sd[3];
        pnd[blockIdx.x]   = sn[0] + sn[1] + sn[2] + sn[3];
    }
}

// ---------------------------------------------------------------------------
// Kernel 2, 2 blocks:
//   block0          : reduce 2048 partials -> energy (~3 us, hidden)
//   block1 wave0.l0 : 100-step lookup walk on lp2
//   block1 waves1-3 : two-phase ring warm -- inner 256 KB around init_idx
//                     FIRST (covers the walk's earliest, coldest steps in
//                     ~2 us), then the full 512 KB window (inner re-touch
//                     is an L2 hit, cheap)
// ---------------------------------------------------------------------------
__global__ __launch_bounds__(256) void qpe_tail(
    const float* __restrict__ x,     const float* __restrict__ lp2,
    const float* __restrict__ pdens, const float* __restrict__ pnd,
    const float* __restrict__ noise, const int* __restrict__ init_idx,
    float* __restrict__ out,         float* __restrict__ dummy)
{
    const int tid = threadIdx.x;
    if (blockIdx.x == 0) {
        float d = 0.f, n = 0.f;
        #pragma unroll
        for (int k = 0; k < 8; ++k) {
            d += pdens[tid + 256 * k];
            n += pnd[tid + 256 * k];
        }
        #pragma unroll
        for (int off = 32; off; off >>= 1) {
            d += __shfl_down(d, off);
            n += __shfl_down(n, off);
        }
        __shared__ float sd[4], sn[4];
        const int lane = tid & 63;
        const int wid  = tid >> 6;
        if (lane == 0) { sd[wid] = d; sn[wid] = n; }
        __syncthreads();
        if (tid == 0) {
            const float Sd = sd[0] + sd[1] + sd[2] + sd[3];
            const float Sn = sn[0] + sn[1] + sn[2] + sn[3];
            out[2 * NPTS] = __fdiv_rn(Sd * DXF, fmaf(Sn, DXF, 1e-8f));
        }
        return;
    }

    if (tid == 0) {
        int c = init_idx[0];
        float zn = noise[0];
        for (int t = 0; t < STEPS; ++t) {
            const float zs = __fmul_rn(zn, SQRT2DT);
            const int tn = (t + 1 < STEPS) ? t + 1 : t;
            zn = noise[tn];                  // prefetch next step's noise
            float s = 0.0f;
            if (c > 0 && c < NPTS - 1) {
                const float l2m = lp2[c - 1];
                const float l2p = lp2[c + 1];
                s = __fmul_rn(__fsub_rn(l2p, l2m), LN2_O_2DX);
            }
            const float a = __fadd_rn(__fmul_rn(s, DTF), zs);
            const int shift = (int)__fdiv_rn(a, DXF);
            c += shift;
            c = c < 0 ? 0 : (c > NPTS - 1 ? NPTS - 1 : c);
        }
        out[2 * NPTS + 1] = x[c];
    } else if (tid >= 64) {
        const int l = tid - 64;              // 0..191
        const int c0 = init_idx[0];
        float acc = 0.f;

        // phase 1: inner 256 KB (16K float4) centered on c0
        int s4i = c0 / 4 - 8192;
        if (s4i < 0) s4i = 0;
        if (s4i > NPTS / 4 - 16384) s4i = NPTS / 4 - 16384;
        const float4* __restrict__ srci = (const float4*)lp2 + s4i;
        #pragma unroll 8
        for (int k = l; k < 16384; k += 192) {
            const float4 v = srci[k];
            acc += v.x + v.y + v.z + v.w;
        }

        // phase 2: full 512 KB (32K float4) window
        int s4 = c0 / 4 - 16384;
        if (s4 < 0) s4 = 0;
        if (s4 > NPTS / 4 - 32768) s4 = NPTS / 4 - 32768;
        const float4* __restrict__ src = (const float4*)lp2 + s4;
        #pragma unroll 8
        for (int k = l; k < 32768; k += 192) {
            const float4 v = src[k];
            acc += v.x + v.y + v.z + v.w;
        }
        if (acc == 123456.789f) dummy[0] = acc;   // keep loads alive
    }
}

// ---------------------------------------------------------------------------
extern "C" void kernel_launch(void* const* d_in, const int* in_sizes, int n_in,
                              void* d_out, int out_size, void* d_ws, size_t ws_size,
                              hipStream_t stream) {
    const float* x        = (const float*)d_in[0];
    const float* V        = (const float*)d_in[1];
    const float* W1       = (const float*)d_in[2];
    const float* b1       = (const float*)d_in[3];
    const float* W2       = (const float*)d_in[4];
    const float* b2       = (const float*)d_in[5];
    const float* noise    = (const float*)d_in[6];
    const int*   init_idx = (const int*)d_in[7];

    float* out = (float*)d_out;
    float* ws  = (float*)d_ws;

    float* lp2   = ws;                      // N floats (2 MB)
    float* wk    = ws + NPTS;               // 1536 (pad to 2048)
    float* pdens = ws + NPTS + 2048;        // 2048
    float* pnd   = ws + NPTS + 4096;        // 2048
    float* dummy = ws + NPTS + 6144;        // 1

    qpe_prep<<<1, 256, 0, stream>>>(W1, b1, W2, wk);
    qpe_main<<<NBLK1, 256, 0, stream>>>(x, V, wk, b2, out, lp2, pdens, pnd);
    qpe_tail<<<2, 256, 0, stream>>>(x, lp2, pdens, pnd, noise, init_idx,
                                    out, dummy);
}